// Round 1
// baseline (1378.357 us; speedup 1.0000x reference)
//
#include <hip/hip_runtime.h>

#define NN 20000
#define NE 200000
#define NG 512

constexpr int EB = 16;   // edges staged per batch
constexpr int BN = 8;    // nodes per workgroup

__device__ __forceinline__ int lowerb(const int* a, int n, int v){
  int lo=0, hi=n;
  while(lo<hi){ int m=(lo+hi)>>1; if(a[m]<v) lo=m+1; else hi=m; }
  return lo;
}

// ---------------- sorting (counting sort by tgt -> CSR) ----------------
__global__ void k_count(const int* __restrict__ tgt, int* __restrict__ cnt){
  int e = blockIdx.x*blockDim.x + threadIdx.x;
  if(e<NE) atomicAdd(&cnt[tgt[e]], 1);
}

__global__ void k_scan(const int* __restrict__ cnt, int* __restrict__ row_start){
  __shared__ int part[1024];
  int t = threadIdx.x;
  const int CH = (NN + 1023)/1024; // 20
  int i0 = t*CH;
  int s = 0;
  for(int j=0;j<CH;j++){ int i=i0+j; if(i<NN) s += cnt[i]; }
  part[t] = s; __syncthreads();
  for(int d=1; d<1024; d<<=1){
    int v = (t>=d) ? part[t-d] : 0;
    __syncthreads();
    part[t] += v;
    __syncthreads();
  }
  int run = (t==0) ? 0 : part[t-1];
  for(int j=0;j<CH;j++){ int i=i0+j; if(i<NN){ row_start[i]=run; run += cnt[i]; } }
  if(t==0) row_start[NN] = part[1023];
}

__global__ void k_place(const int* __restrict__ src, const int* __restrict__ tgt,
                        const int* __restrict__ row_start, int* __restrict__ cur,
                        int* __restrict__ es_src, int* __restrict__ es_eid){
  int e = blockIdx.x*blockDim.x + threadIdx.x;
  if(e>=NE) return;
  int n = tgt[e];
  int pos = row_start[n] + atomicAdd(&cur[n],1);
  es_src[pos] = src[e];
  es_eid[pos] = e;
}

// ---------------- fused NNConv layer (scatter S in LDS + GEMM vs W2) ----------------
// agg[n,o] = sum_k S[n,k]*W2[p0*IC + k, o]  (+ xbar-term for split 0), k = p_local*IC+i
// S[n,p,i] = sum_{e in in(n)} relu(ea[e]@W1+b1)[p0+p]/deg(n) * x[src[e], i]
template<int IC, int OC, int PLEN, int KS, int PT, int IT, int TI, int TPH>
__launch_bounds__(256, 2)
__global__ void k_layer(const float* __restrict__ x_in, const float* __restrict__ ea,
                        const int* __restrict__ es_src, const int* __restrict__ es_eid,
                        const int* __restrict__ row_start,
                        const float* __restrict__ W1, const float* __restrict__ b1,
                        const float* __restrict__ W2, const float* __restrict__ b2,
                        float* __restrict__ agg)
{
  constexpr int K  = PLEN*IC;
  constexpr int OH = OC/2;
  constexpr int KC = 256/OH;

  __shared__ __align__(16) float S[BN*PLEN*IC];
  __shared__ float xbar[BN*IC];
  __shared__ float W1s[16*PLEN];
  __shared__ float b1s[PLEN];
  __shared__ __align__(16) float hbuf[EB*PLEN];
  __shared__ __align__(16) float eas[EB*16];
  __shared__ __align__(16) float xs[EB*IC];
  __shared__ float dinvs[EB];
  __shared__ int ro[BN+1];

  const int tid = threadIdx.x;
  const int split = blockIdx.x % KS;
  const int nb = blockIdx.x / KS;
  const int n0 = nb*BN;
  const int p0 = split*PLEN;

  for(int i=tid; i<BN*PLEN*IC; i+=256) S[i]=0.f;
  for(int i=tid; i<BN*IC; i+=256) xbar[i]=0.f;
  for(int i=tid; i<16*PLEN; i+=256){ int r=i/PLEN, c=i%PLEN; W1s[i] = W1[r*128 + p0 + c]; }
  for(int i=tid; i<PLEN; i+=256) b1s[i] = b1[p0+i];

  const int estart = row_start[n0];
  const int eend   = row_start[n0+BN];
  __syncthreads();

  for(int bstart = estart; bstart < eend; bstart += EB){
    const int ebc = min(EB, eend - bstart);
    // ---- phase 1: stage run offsets, edge_attr, x[src]
    if(tid <= BN){
      int rs = row_start[n0+tid];
      ro[tid] = min(max(rs - bstart, 0), ebc);
    }
    for(int j=tid; j<ebc*4; j+=256){
      int e = j>>2, q = j&3;
      int eid = es_eid[bstart+e];
      ((float4*)eas)[e*4+q] = ((const float4*)ea)[eid*4+q];
    }
    constexpr int XV = IC/4;
    for(int j=tid; j<ebc*XV; j+=256){
      int e = j/XV, q = j%XV;
      int sn = es_src[bstart+e];
      ((float4*)xs)[e*XV+q] = ((const float4*)x_in)[sn*XV+q];
    }
    __syncthreads();
    // ---- phase 2: edge MLP h~ = relu(ea@W1+b1)/deg
    {
      int e = tid>>4, pg = tid&15;
      if(e < ebc){
        int nl = 0;
        while(ro[nl+1] <= e) nl++;
        float degf = (float)(row_start[n0+nl+1]-row_start[n0+nl]);
        float dinv = 1.f/fmaxf(degf, 1.f);
        if(pg==0) dinvs[e] = dinv;
        float eav[16];
        #pragma unroll
        for(int q=0;q<4;q++){
          float4 v = ((float4*)eas)[e*4+q];
          eav[q*4+0]=v.x; eav[q*4+1]=v.y; eav[q*4+2]=v.z; eav[q*4+3]=v.w;
        }
        #pragma unroll
        for(int t2=0; t2<TPH; t2++){
          int p = pg + 16*t2;
          float hv = b1s[p];
          #pragma unroll
          for(int i=0;i<16;i++) hv += eav[i]*W1s[i*PLEN+p];
          hbuf[e*PLEN+p] = fmaxf(hv, 0.f)*dinv;
        }
      }
    }
    __syncthreads();
    // ---- phase 3: scatter outer products into S (exclusive (p,i)-tile per thread)
    {
      int pt = tid / IT, it = tid % IT;
      int ibase = it*TI;
      for(int nl=0; nl<BN; nl++){
        int a = ro[nl], b = ro[nl+1];
        if(a>=b) continue;
        float acc0[TI], acc1[TI], xacc[TI];
        #pragma unroll
        for(int u=0;u<TI;u++){ acc0[u]=0.f; acc1[u]=0.f; xacc[u]=0.f; }
        for(int e=a; e<b; e++){
          float2 h2 = *(float2*)&hbuf[e*PLEN + pt*2];
          float dv = dinvs[e];
          #pragma unroll
          for(int u=0;u<TI;u++){
            float xv = xs[e*IC + ibase + u];
            acc0[u] += h2.x*xv;
            acc1[u] += h2.y*xv;
            if(pt==0) xacc[u] += dv*xv;
          }
        }
        #pragma unroll
        for(int u=0;u<TI;u++){
          S[((nl*PLEN)+(pt*2  ))*IC + ibase + u] += acc0[u];
          S[((nl*PLEN)+(pt*2+1))*IC + ibase + u] += acc1[u];
        }
        if(pt==0){
          #pragma unroll
          for(int u=0;u<TI;u++) xbar[nl*IC + ibase + u] += xacc[u];
        }
      }
    }
    __syncthreads();
  }

  // ---- GEMM phase: agg_partial[n,o] = sum_k S[n,k] * W2[p0*IC+k, o]
  int og = tid % OH;
  int kc = tid / OH;
  float acc[BN][2];
  #pragma unroll
  for(int n=0;n<BN;n++){ acc[n][0]=0.f; acc[n][1]=0.f; }
  if(kc < KC){
    const float* W2p = W2 + (size_t)(p0*IC)*OC + 2*og;
    for(int kb = kc; kb < K/4; kb += KC){
      int k = kb*4;
      float4 sv[BN];
      #pragma unroll
      for(int n=0;n<BN;n++) sv[n] = ((float4*)S)[(n*K + k)>>2];
      float2 w0 = *(const float2*)&W2p[(k+0)*OC];
      float2 w1 = *(const float2*)&W2p[(k+1)*OC];
      float2 w2 = *(const float2*)&W2p[(k+2)*OC];
      float2 w3 = *(const float2*)&W2p[(k+3)*OC];
      #pragma unroll
      for(int n=0;n<BN;n++){
        acc[n][0] += sv[n].x*w0.x + sv[n].y*w1.x + sv[n].z*w2.x + sv[n].w*w3.x;
        acc[n][1] += sv[n].x*w0.y + sv[n].y*w1.y + sv[n].z*w2.y + sv[n].w*w3.y;
      }
    }
  }
  __syncthreads();        // done reading S; reuse as partial-sum area
  float* pr = S;
  if(kc < KC){
    #pragma unroll
    for(int n=0;n<BN;n++){ pr[tid*16 + n*2+0] = acc[n][0]; pr[tid*16 + n*2+1] = acc[n][1]; }
  }
  __syncthreads();
  for(int t = tid; t < BN*OC; t += 256){
    int n = t / OC, o = t % OC;
    int oh = o>>1, ol = o&1;
    float sum = 0.f;
    for(int q=0;q<KC;q++) sum += pr[(oh + OH*q)*16 + n*2 + ol];
    if(split==0){
      for(int i=0;i<IC;i++) sum += xbar[n*IC+i]*b2[i*OC+o];
    }
    atomicAdd(&agg[(size_t)(n0+n)*OC + o], sum);
  }
}

// ---------------- epilogue: y = relu(agg + x@root + bias) ----------------
template<int IC, int OC>
__global__ void k_epi(const float* __restrict__ agg, const float* __restrict__ x,
                      const float* __restrict__ root, const float* __restrict__ bias,
                      float* __restrict__ y)
{
  int idx = blockIdx.x*256 + threadIdx.x;
  if(idx >= NN*OC) return;
  int n = idx/OC, o = idx%OC;
  float v = agg[idx] + bias[o];
  for(int i=0;i<IC;i++) v += x[n*IC+i]*root[i*OC+o];
  y[idx] = fmaxf(v, 0.f);
}

// ---------------- set2set (2 steps) + final MLP, one workgroup (1 wave) per graph ----------------
__global__ void k_s2s(const float* __restrict__ xg, const int* __restrict__ batch,
  const float* __restrict__ Wih, const float* __restrict__ Whh,
  const float* __restrict__ bih, const float* __restrict__ bhh,
  const float* __restrict__ l1W, const float* __restrict__ l1b,
  const float* __restrict__ l2W, const float* __restrict__ l2b,
  const float* __restrict__ lfW, const float* __restrict__ lfb,
  float* __restrict__ out)
{
  int g = blockIdx.x, lane = threadIdx.x;
  __shared__ float hs[16], cs[16], qs[32], gs[64], rs[16];
  int r0 = lowerb(batch, NN, g);
  int r1 = lowerb(batch, NN, g+1);
  if(lane<16){ hs[lane]=0.f; cs[lane]=0.f; }
  if(lane<32) qs[lane]=0.f;
  __syncthreads();
  for(int step=0; step<2; step++){
    // LSTM cell: gates = q_star@Wih^T + bih + h@Whh^T + bhh
    float gate = bih[lane] + bhh[lane];
    for(int k=0;k<32;k++) gate += qs[k]*Wih[lane*32+k];
    for(int k=0;k<16;k++) gate += hs[k]*Whh[lane*16+k];
    gs[lane] = gate;
    __syncthreads();
    if(lane<16){
      float ig = 1.f/(1.f+expf(-gs[lane]));
      float fg = 1.f/(1.f+expf(-gs[lane+16]));
      float gg = tanhf(gs[lane+32]);
      float og = 1.f/(1.f+expf(-gs[lane+48]));
      float cn = fg*cs[lane] + ig*gg;
      cs[lane] = cn;
      hs[lane] = og*tanhf(cn);
    }
    __syncthreads();
    // attention (online softmax over this graph's nodes)
    float m = -1e30f;
    for(int n=r0+lane; n<r1; n+=64){
      float e=0.f;
      for(int k=0;k<16;k++) e += xg[n*16+k]*hs[k];
      m = fmaxf(m, e);
    }
    for(int d=1; d<64; d<<=1) m = fmaxf(m, __shfl_xor(m, d));
    float ssum = 0.f;
    float racc[16];
    #pragma unroll
    for(int k=0;k<16;k++) racc[k]=0.f;
    for(int n=r0+lane; n<r1; n+=64){
      float e=0.f, xv[16];
      #pragma unroll
      for(int k=0;k<16;k++){ xv[k]=xg[n*16+k]; e += xv[k]*hs[k]; }
      float a = expf(e - m);
      ssum += a;
      #pragma unroll
      for(int k=0;k<16;k++) racc[k] += a*xv[k];
    }
    for(int d=1; d<64; d<<=1) ssum += __shfl_xor(ssum, d);
    #pragma unroll
    for(int k=0;k<16;k++)
      for(int d=1; d<64; d<<=1) racc[k] += __shfl_xor(racc[k], d);
    ssum = fmaxf(ssum, 1e-16f);
    if(lane==0){
      #pragma unroll
      for(int k=0;k<16;k++) rs[k] = racc[k]/ssum;
    }
    __syncthreads();
    if(lane<16){ qs[lane]=hs[lane]; qs[16+lane]=rs[lane]; }
    __syncthreads();
  }
  // final MLP: 32 -> 16 -> 8 -> 1
  if(lane<16){
    float v = l1b[lane];
    for(int k=0;k<32;k++) v += qs[k]*l1W[k*16+lane];
    gs[lane] = fmaxf(v,0.f);
  }
  __syncthreads();
  if(lane<8){
    float v = l2b[lane];
    for(int k=0;k<16;k++) v += gs[k]*l2W[k*8+lane];
    gs[32+lane] = fmaxf(v,0.f);
  }
  __syncthreads();
  if(lane==0){
    float v = lfb[0];
    for(int k=0;k<8;k++) v += gs[32+k]*lfW[k];
    out[g] = v;
  }
}

extern "C" void kernel_launch(void* const* d_in, const int* in_sizes, int n_in,
                              void* d_out, int out_size, void* d_ws, size_t ws_size,
                              hipStream_t stream) {
  const float* x0   = (const float*)d_in[0];
  const int*   ei   = (const int*)d_in[1];
  const float* ea   = (const float*)d_in[2];
  const int*   batch= (const int*)d_in[3];
  const float* c1W1 = (const float*)d_in[4];  const float* c1b1 = (const float*)d_in[5];
  const float* c1W2 = (const float*)d_in[6];  const float* c1b2 = (const float*)d_in[7];
  const float* c1rt = (const float*)d_in[8];  const float* c1bs = (const float*)d_in[9];
  const float* c2W1 = (const float*)d_in[10]; const float* c2b1 = (const float*)d_in[11];
  const float* c2W2 = (const float*)d_in[12]; const float* c2b2 = (const float*)d_in[13];
  const float* c2rt = (const float*)d_in[14]; const float* c2bs = (const float*)d_in[15];
  const float* c3W1 = (const float*)d_in[16]; const float* c3b1 = (const float*)d_in[17];
  const float* c3W2 = (const float*)d_in[18]; const float* c3b2 = (const float*)d_in[19];
  const float* c3rt = (const float*)d_in[20]; const float* c3bs = (const float*)d_in[21];
  const float* Wih  = (const float*)d_in[22]; const float* Whh  = (const float*)d_in[23];
  const float* bih  = (const float*)d_in[24]; const float* bhh  = (const float*)d_in[25];
  const float* l1W  = (const float*)d_in[26]; const float* l1b  = (const float*)d_in[27];
  const float* l2W  = (const float*)d_in[28]; const float* l2b  = (const float*)d_in[29];
  const float* lfW  = (const float*)d_in[30]; const float* lfb  = (const float*)d_in[31];
  float* out = (float*)d_out;

  const int* src = ei;
  const int* tgt = ei + NE;

  // workspace carve (~14 MB)
  char* w = (char*)d_ws;
  auto carve = [&](size_t bytes)->void*{ void* p = (void*)w; w += (bytes + 255) & ~(size_t)255; return p; };
  int*   row_start = (int*)carve((NN+1)*sizeof(int));
  int*   cur       = (int*)carve(NN*sizeof(int));
  int*   es_src    = (int*)carve(NE*sizeof(int));
  int*   es_eid    = (int*)carve(NE*sizeof(int));
  float* y1  = (float*)carve((size_t)NN*48*sizeof(float));
  float* y2  = (float*)carve((size_t)NN*32*sizeof(float));
  float* y3  = (float*)carve((size_t)NN*16*sizeof(float));
  float* agg = (float*)carve((size_t)NN*48*sizeof(float));

  // ---- CSR by tgt
  hipMemsetAsync(cur, 0, NN*sizeof(int), stream);
  k_count<<<(NE+255)/256, 256, 0, stream>>>(tgt, cur);
  k_scan<<<1, 1024, 0, stream>>>(cur, row_start);
  hipMemsetAsync(cur, 0, NN*sizeof(int), stream);
  k_place<<<(NE+255)/256, 256, 0, stream>>>(src, tgt, row_start, cur, es_src, es_eid);

  const int NB = NN/BN; // 2500

  // ---- layer 1: IC=16 OC=48, PLEN=64 KS=2
  hipMemsetAsync(agg, 0, (size_t)NN*48*sizeof(float), stream);
  k_layer<16,48,64,2, 32,8,2, 4><<<NB*2, 256, 0, stream>>>(x0, ea, es_src, es_eid, row_start, c1W1, c1b1, c1W2, c1b2, agg);
  k_epi<16,48><<<(NN*48+255)/256, 256, 0, stream>>>(agg, x0, c1rt, c1bs, y1);

  // ---- layer 2: IC=48 OC=32, PLEN=32 KS=4
  hipMemsetAsync(agg, 0, (size_t)NN*32*sizeof(float), stream);
  k_layer<48,32,32,4, 16,16,3, 2><<<NB*4, 256, 0, stream>>>(y1, ea, es_src, es_eid, row_start, c2W1, c2b1, c2W2, c2b2, agg);
  k_epi<48,32><<<(NN*32+255)/256, 256, 0, stream>>>(agg, y1, c2rt, c2bs, y2);

  // ---- layer 3: IC=32 OC=16, PLEN=32 KS=4
  hipMemsetAsync(agg, 0, (size_t)NN*16*sizeof(float), stream);
  k_layer<32,16,32,4, 16,16,2, 2><<<NB*4, 256, 0, stream>>>(y2, ea, es_src, es_eid, row_start, c3W1, c3b1, c3W2, c3b2, agg);
  k_epi<32,16><<<(NN*16+255)/256, 256, 0, stream>>>(agg, y2, c3rt, c3bs, y3);

  // ---- set2set + MLP head
  k_s2s<<<NG, 64, 0, stream>>>(y3, batch, Wih, Whh, bih, bhh, l1W, l1b, l2W, l2b, lfW, lfb, out);
}